// Round 7
// baseline (282.909 us; speedup 1.0000x reference)
//
#include <hip/hip_runtime.h>
#include <math.h>

typedef __attribute__((ext_vector_type(8))) short bf16x8;
typedef __attribute__((ext_vector_type(4))) float f32x4;
typedef __attribute__((ext_vector_type(4))) unsigned int u32x4;

#define SGB(mask, n) __builtin_amdgcn_sched_group_barrier((mask), (n), 0)
// masks: MFMA=0x8, VMEM_READ=0x20, DS_READ=0x100

__device__ __forceinline__ unsigned f2bf(float f) {
    union { float f; unsigned u; } v; v.f = f;
    return (v.u + 0x7FFFu + ((v.u >> 16) & 1u)) >> 16;   // RTNE bf16
}

// Build conv kernel in bf16, layout Kb[tap][o][i] (i contiguous), taps 0..125
// with tap 125 all-zero (pad for tap-pairing). Self-interaction folded into
// center tap (62), x10 since out = 0.1*conv_total.
__global__ __launch_bounds__(256) void build_K(
    const float* __restrict__ w_lin0,
    const float* __restrict__ w_lin1,
    const float* __restrict__ tp_weight,
    unsigned short* __restrict__ Kb)
{
    const int tid = (int)threadIdx.x;
    const int tap = (int)blockIdx.x;            // 0..125
    if (tap == 125) {
        for (int n = tid; n < 4096; n += 256) Kb[125 * 4096 + n] = 0;
        return;
    }
    const int i1 = tap / 25, i2 = (tap / 5) % 5, i3 = tap % 5;
    const float X = -1.0f + 0.5f * (float)i1;
    const float Y = -1.0f + 0.5f * (float)i2;
    const float Z = -1.0f + 0.5f * (float)i3;
    const float d = sqrtf(X*X + Y*Y + Z*Z);
    const float dinv = 1.0f / fmaxf(d, 1e-12f);
    const float vx = X * dinv, vy = Y * dinv, vz = Z * dinv;
    const float r2 = vx*vx + vy*vy + vz*vz;

    __shared__ float wsh[1280];
    __shared__ float y1s[3];
    __shared__ float Qs[9];

    if (tid == 0) {
        const float s3 = 1.7320508075688772f;
        const float s15 = 3.872983346207417f;
        y1s[0] = s3 * vy; y1s[1] = s3 * vz; y1s[2] = s3 * vx;
        float y2v0 = s15 * vx * vy;
        float y2v1 = s15 * vy * vz;
        float y2v2 = 1.118033988749895f * (3.0f * vz * vz - r2);
        float y2v3 = s15 * vx * vz;
        float y2v4 = 1.9364916731037085f * (vx * vx - vy * vy);
        const float INV10 = 0.31622776601683794f;
        const float INV30 = 0.18257418583505536f;
        Qs[0] = -y2v2 * INV30 - y2v4 * INV10;
        Qs[4] =  2.0f * y2v2 * INV30;
        Qs[8] = -y2v2 * INV30 + y2v4 * INV10;
        Qs[1] = Qs[3] = y2v1 * INV10;
        Qs[2] = Qs[6] = y2v0 * INV10;
        Qs[5] = Qs[7] = y2v3 * INV10;
    }

    float emb[5];
    #pragma unroll
    for (int e = 0; e < 5; ++e) {
        float t = (d - 0.25f * (float)e) * 4.0f;
        emb[e] = expf(-t * t) * (1.0f / 1.12f);
    }
    const float scale = cosf(3.14159265358979323846f * d) / 11.180339887498949f;

    for (int j = tid; j < 1280; j += 256) {
        float s = 0.0f;
        #pragma unroll
        for (int e = 0; e < 5; ++e) s += emb[e] * tp_weight[e * 1280 + j];
        wsh[j] = scale * s;
    }
    __syncthreads();

    const float F0   = 0.17677669529663687f;
    const float F1   = 0.25f;
    const float F0S3 = 0.10206207261596574f;
    const float F1S3 = 0.14433756729740646f;

    #pragma unroll 1
    for (int n = 0; n < 16; ++n) {
        int e = n * 256 + tid;
        int o = e & 63, i = e >> 6;
        float Kv;
        if (o < 16) {
            if (i < 16) {
                Kv = F0 * wsh[0 * 256 + i * 16 + o];
            } else {
                int u = (i - 16) / 3, a = (i - 16) % 3;
                Kv = F0S3 * y1s[a] * wsh[3 * 256 + u * 16 + o];
            }
        } else {
            int wcol = (o - 16) / 3, c = (o - 16) % 3;
            if (i < 16) {
                Kv = F1S3 * y1s[c] * wsh[1 * 256 + i * 16 + wcol];
            } else {
                int u = (i - 16) / 3, a = (i - 16) % 3;
                Kv = F1 * Qs[a * 3 + c] * wsh[4 * 256 + u * 16 + wcol];
                if (a == c) Kv += F1S3 * wsh[2 * 256 + u * 16 + wcol];
            }
        }
        if (tap == 62) {
            if (o < 16) {
                if (i < 16) Kv += 2.5f * w_lin0[i * 16 + o];
            } else if (i >= 16) {
                int v = (o - 16) / 3, m = (o - 16) % 3;
                int u = (i - 16) / 3, a = (i - 16) % 3;
                if (a == m) Kv += 2.5f * w_lin1[u * 16 + v];
            }
        }
        Kb[(tap * 64 + o) * 64 + i] = (unsigned short)f2bf(Kv);
    }
}

// Pre-pass: x fp32 [b][c][32^3] -> xbz bf16 channel-last [b][pos][64ch],
// preceded by a 128B zero page (for OOB halo lanes).
__global__ __launch_bounds__(256) void to_blc(
    const float* __restrict__ x,
    unsigned short* __restrict__ xbz)
{
    const int tid = (int)threadIdx.x, blk = (int)blockIdx.x;
    if (blk == 0 && tid < 64) xbz[tid] = 0;          // zero page
    const int p = blk * 256 + tid;                   // 0..131071
    const int b = p >> 15, pos = p & 32767;
    const float* xp = x + ((size_t)b << 21) + pos;
    unsigned short* op = xbz + 64 + (size_t)p * 64;
    #pragma unroll
    for (int cg = 0; cg < 8; ++cg) {
        u32x4 dv;
        #pragma unroll
        for (int jj = 0; jj < 4; ++jj) {
            float f0 = xp[((size_t)(cg * 8 + 2 * jj)) << 15];
            float f1 = xp[((size_t)(cg * 8 + 2 * jj + 1)) << 15];
            dv[jj] = f2bf(f0) | (f2bf(f1) << 16);
        }
        *(u32x4*)(op + cg * 8) = dv;
    }
}

// Implicit-GEMM conv via MFMA 16x16x32 bf16. TLP-first variant:
// grid 1024, block = 2z x 8y x 8x = 128 pos, all 64 o, 4 waves.
// Wave (zp = wv>>1, h = wv&1): 2 mo (16-o tiles of o-half h) x 4 np (z-plane
// zp). acc 32 VGPR; Ab ring 3 slots/dist 2; xn ring 2 slots/dist 1; ~120
// VGPR total under __launch_bounds__(256,4) so rings can materialize.
// Single 27.6 KB LDS buffer (XOR-16 swizzle) -> 4-5 blocks/CU.
__global__ __launch_bounds__(256, 4) void conv_mfma(
    const unsigned short* __restrict__ xbz,
    const unsigned short* __restrict__ Kb,
    float* __restrict__ out)
{
    __shared__ __align__(16) char xs[27648];   // [6z][12y][12x] * 32B

    const int tid = (int)threadIdx.x;
    const int blk = (int)blockIdx.x;
    const int xt = blk & 3, yt = (blk >> 2) & 3, zt = (blk >> 4) & 15, b = blk >> 8;
    const int lane = tid & 63, wv = tid >> 6;
    const int r = lane & 15, g = lane >> 4;
    const int thalf = g >> 1, chslot = g & 1;
    const bool thv = (thalf != 0);
    const int zp = wv >> 1, h = wv & 1;

    // ---- staging source offsets (7 chunks/thread; 1728 chunks total) ----
    unsigned srcOff[7];
    {
        const int gz0 = zt * 2 - 2, gy0 = yt * 8 - 2, gx0 = xt * 8 - 2;
        #pragma unroll
        for (int i = 0; i < 7; ++i) {
            int tau = tid + i * 256;
            int pos = tau >> 1, slot = tau & 1;
            int hz = pos / 144; int rem = pos - hz * 144;
            int hy = rem / 12;  int hx = rem - hy * 12;
            int gz = gz0 + hz, gy = gy0 + hy, gx = gx0 + hx;
            bool ok = ((unsigned)gz < 32u) && ((unsigned)gy < 32u) && ((unsigned)gx < 32u);
            int pg = (gz << 10) + (gy << 5) + gx;
            unsigned chs = (unsigned)(slot ^ ((hx >> 2) & 1));  // swizzle-inverse
            srcOff[i] = ok ? (unsigned)(128 + (((b << 15) + pg) << 7) + chs * 16)
                           : (unsigned)(slot * 16);             // zero page
        }
    }

    // ---- per-lane swizzled x/ch part for dx=0..4 ----
    int sax[5];
    #pragma unroll
    for (int dx = 0; dx < 5; ++dx) {
        int xx = (r & 7) + dx;
        sax[dx] = (xx * 32 + chslot * 16) ^ ((xx & 4) << 2);
    }
    // per-np base (z-plane + y part)
    int nbase[4];
    #pragma unroll
    for (int n = 0; n < 4; ++n)
        nbase[n] = zp * 4608 + (2 * n + (r >> 3)) * 384;

    const char* kbl = (const char*)Kb + r * 128 + thalf * 8192 + chslot * 16 + h * 4096;

    f32x4 acc[2][4];
    #pragma unroll
    for (int m = 0; m < 2; ++m)
        #pragma unroll
        for (int n = 0; n < 4; ++n) acc[m][n] = (f32x4)0.0f;

    // tap-pair -> (dz*4608 + dy*384 + sax[dx]) for this lane's half
#define TB(P) ((2 * (P) + 1 == 125) ? 124 : 2 * (P) + 1)
#define PD(P)                                                                  \
    (thv ? (((TB(P)) / 25) * 4608 + (((TB(P)) / 5) % 5) * 384 + sax[(TB(P)) % 5]) \
         : (((2 * (P)) / 25) * 4608 + (((2 * (P)) / 5) % 5) * 384 + sax[(2 * (P)) % 5]))

    #pragma unroll 1
    for (int stage = 0; stage < 4; ++stage) {
        const char* kbs = kbl + stage * 32;

        // Ab ring prologue (pairs 0,1) — issued before staging DMAs so their
        // waits don't FIFO-wait on the gather
        bf16x8 Ab[3][2];
        #pragma unroll
        for (int pf = 0; pf < 2; ++pf)
            #pragma unroll
            for (int m = 0; m < 2; ++m)
                Ab[pf][m] = *(const bf16x8*)(kbs + pf * 16384 + m * 2048);
        SGB(0x20, 4);

        __syncthreads();                  // prev stage's LDS reads complete
        #pragma unroll
        for (int i = 0; i < 7; ++i) {
            if (tid + i * 256 < 1728) {
                const char* src = (const char*)xbz + srcOff[i] + stage * 32;
                __builtin_amdgcn_global_load_lds(
                    (const __attribute__((address_space(1))) unsigned int*)src,
                    (__attribute__((address_space(3))) unsigned int*)
                        (xs + i * 4096 + wv * 1024),
                    16, 0, 0);
            }
        }
        __syncthreads();                  // staging complete (vmcnt drain)

        bf16x8 xn[2][4];
        {
            int d0 = PD(0);
            #pragma unroll
            for (int n = 0; n < 4; ++n)
                xn[0][n] = *(const bf16x8*)&xs[nbase[n] + d0];
        }
        SGB(0x100, 4);

        #pragma unroll
        for (int P = 0; P < 63; ++P) {
            if (P < 61) {
                #pragma unroll
                for (int m = 0; m < 2; ++m)
                    Ab[(P + 2) % 3][m] =
                        *(const bf16x8*)(kbs + (P + 2) * 16384 + m * 2048);
                SGB(0x20, 2);
            }
            if (P < 62) {
                int d = PD(P + 1);
                #pragma unroll
                for (int n = 0; n < 4; ++n)
                    xn[(P + 1) & 1][n] = *(const bf16x8*)&xs[nbase[n] + d];
                SGB(0x100, 4);
            }
            #pragma unroll
            for (int m = 0; m < 2; ++m)
                #pragma unroll
                for (int n = 0; n < 4; ++n)
                    acc[m][n] = __builtin_amdgcn_mfma_f32_16x16x32_bf16(
                        Ab[P % 3][m], xn[P & 1][n], acc[m][n], 0, 0, 0);
            SGB(0x8, 8);
        }
    }
#undef PD
#undef TB

    // epilogue: D row = o-in-half = g*4+reg, col = pos-in-np-tile = r
    const int gz = zt * 2 + zp;
    #pragma unroll
    for (int m = 0; m < 2; ++m) {
        #pragma unroll
        for (int reg = 0; reg < 4; ++reg) {
            int o = h * 32 + m * 16 + g * 4 + reg;
            float* op = out + (((size_t)(b * 64 + o)) << 15) + (gz << 10);
            #pragma unroll
            for (int n = 0; n < 4; ++n) {
                int ly = 2 * n + (r >> 3), lx = r & 7;
                op[((yt * 8 + ly) << 5) + (xt * 8 + lx)] = 0.1f * acc[m][n][reg];
            }
        }
    }
}

extern "C" void kernel_launch(void* const* d_in, const int* in_sizes, int n_in,
                              void* d_out, int out_size, void* d_ws, size_t ws_size,
                              hipStream_t stream) {
    const float* x       = (const float*)d_in[0];
    const float* w_lin0  = (const float*)d_in[1];
    const float* w_lin1  = (const float*)d_in[2];
    const float* tp      = (const float*)d_in[3];
    unsigned short* Kb  = (unsigned short*)d_ws;                        // ~1.03 MB
    unsigned short* xbz = (unsigned short*)((char*)d_ws + (2u << 20));  // 128B zeros + 16.8MB bf16 x
    float* out = (float*)d_out;

    build_K<<<126, 256, 0, stream>>>(w_lin0, w_lin1, tp, Kb);
    to_blc<<<512, 256, 0, stream>>>(x, xbz);
    conv_mfma<<<1024, 256, 0, stream>>>(xbz, Kb, out);
}